// Round 7
// baseline (71.745 us; speedup 1.0000x reference)
//
#include <hip/hip_runtime.h>
#include <math.h>

// out (32,64,16,2048) f32 = one_hot(ascending-sorted top-16 indices of logits+gn).
// Forward value of stop_gradient(hard-soft)+soft == hard exactly (0) / ~1ulp (1).
//
// Fused single kernel, 512 WGs x 256 threads:
//   select: wave w picks top-16 of row 4*bid+w fully in-wave (R1 algorithm),
//           posts the 16 ascending-rank one-hot columns to LDS.
//   write:  after one cheap barrier, the WG streams its contiguous 512KB output
//           window (4 rows) with NONTEMPORAL float4 stores (few long sequential
//           write streams, no L2/L3 dirty-line churn), ones injected inline.
#define K_SEL   16
#define VOCAB   2048
#define NROWS   2048    // BS(32) * D0(64)
#define RPW     4       // rows per workgroup
#define WGS     (NROWS / RPW)

typedef float vf4 __attribute__((ext_vector_type(4)));

__global__ __launch_bounds__(256) void topk_onehot_fused(
    const float* __restrict__ logits,   // (64, 2048)
    const float* __restrict__ gn,       // (32, 64, 2048)
    float* __restrict__ out)            // (32, 64, 16, 2048)
{
    const int bid  = blockIdx.x;
    const int tid  = threadIdx.x;
    const int lane = tid & 63;
    const int w    = tid >> 6;              // wave 0..3
    const int row  = bid * RPW + w;         // this wave's (bs,d0) row
    const int d0   = row & 63;

    __shared__ int onec[RPW][K_SEL];        // ascending-rank one-hot columns

    // ---------------- select: per-wave top-16 of 2048 ----------------
    const float* grow = gn     + (size_t)row * VOCAB;
    const float* lrow = logits + (size_t)d0  * VOCAB;

    // lane owns columns c = seg*256 + lane*4 + j, seg=0..7, j=0..3
    float v[32];
    #pragma unroll
    for (int seg = 0; seg < 8; ++seg) {
        const int c = seg * 256 + lane * 4;
        const float4 g = *reinterpret_cast<const float4*>(grow + c);
        const float4 l = *reinterpret_cast<const float4*>(lrow + c);
        v[seg * 4 + 0] = l.x + g.x;
        v[seg * 4 + 1] = l.y + g.y;
        v[seg * 4 + 2] = l.z + g.z;
        v[seg * 4 + 3] = l.w + g.w;
    }

    // local argmax; ascending scan + strict '>' keeps lowest index on ties
    float lv = v[0]; int ls = 0;
    #pragma unroll
    for (int i = 1; i < 32; ++i) { if (v[i] > lv) { lv = v[i]; ls = i; } }

    int sel[K_SEL];
    #pragma unroll
    for (int k = 0; k < K_SEL; ++k) {
        float bv = lv;
        int   bc = ((ls >> 2) << 8) + lane * 4 + (ls & 3);
        #pragma unroll
        for (int off = 1; off < 64; off <<= 1) {
            const float ov = __shfl_xor(bv, off);
            const int   oc = __shfl_xor(bc, off);
            if (ov > bv || (ov == bv && oc < bc)) { bv = ov; bc = oc; }
        }
        sel[k] = bc;  // wave-uniform
        if (lane == ((bc >> 2) & 63)) {     // owner knocks out + rescans
            const int s = (((bc >> 8) & 7) << 2) | (bc & 3);
            lv = -INFINITY; ls = 0;
            #pragma unroll
            for (int i = 0; i < 32; ++i) {
                if (i == s) v[i] = -INFINITY;
                if (v[i] > lv) { lv = v[i]; ls = i; }
            }
        }
    }

    // lanes 0..15: rank sel[lane] by ascending index (distinct -> permutation)
    if (lane < K_SEL) {
        int my = sel[0];
        #pragma unroll
        for (int k = 1; k < K_SEL; ++k) { if (lane == k) my = sel[k]; }
        int r = 0;
        #pragma unroll
        for (int j = 0; j < K_SEL; ++j) r += (sel[j] < my) ? 1 : 0;
        onec[w][r] = my;
    }
    __syncthreads();    // only loads/LDS outstanding — cheap

    // ---------------- cooperative streaming write: 512KB contiguous ----------------
    // WG window = rows [4*bid, 4*bid+4) = 131072 floats, written front-to-back by
    // all 256 threads together (few long sequential HBM streams), nontemporal.
    float* obase = out + (size_t)bid * (RPW * K_SEL * VOCAB);
    #pragma unroll
    for (int r4 = 0; r4 < RPW; ++r4) {
        #pragma unroll
        for (int k = 0; k < K_SEL; ++k) {
            const int one = onec[r4][k];                 // static LDS addr, broadcast
            float* rbase = obase + ((r4 * K_SEL + k) * VOCAB);
            #pragma unroll
            for (int t = 0; t < 2; ++t) {
                const int c = (t * 256 + tid) * 4;
                vf4 a;
                a.x = (c + 0 == one) ? 1.0f : 0.0f;
                a.y = (c + 1 == one) ? 1.0f : 0.0f;
                a.z = (c + 2 == one) ? 1.0f : 0.0f;
                a.w = (c + 3 == one) ? 1.0f : 0.0f;
                __builtin_nontemporal_store(a, reinterpret_cast<vf4*>(rbase + c));
            }
        }
    }
}

extern "C" void kernel_launch(void* const* d_in, const int* in_sizes, int n_in,
                              void* d_out, int out_size, void* d_ws, size_t ws_size,
                              hipStream_t stream) {
    const float* logits = (const float*)d_in[0];   // 64*2048
    const float* gn     = (const float*)d_in[1];   // 32*64*2048
    float* out          = (float*)d_out;           // 32*64*16*2048

    hipLaunchKernelGGL(topk_onehot_fused, dim3(WGS), dim3(256), 0, stream,
                       logits, gn, out);
}